// Round 6
// baseline (45.207 us; speedup 1.0000x reference)
//
#include <hip/hip_runtime.h>
#include <hip/hip_bf16.h>
#include <math.h>

#define NH 16
#define SL 2048
#define DM 128

typedef float f32x4 __attribute__((ext_vector_type(4)));
typedef short s16x8 __attribute__((ext_vector_type(8)));
typedef short s16x4 __attribute__((ext_vector_type(4)));

static __device__ __forceinline__ short f2bf(float f) {
  __hip_bfloat16 h = __float2bfloat16(f);
  return __builtin_bit_cast(short, h);
}

// 512-thread block = 64 q-rows, split-KV: waves 0-3 (half A) do KV tiles
// [0, ceil(n/2)), waves 4-7 (half B) do [ceil(n/2), n). Each half has its own
// K/V/P LDS buffers (80KB total -> 2 blocks/CU -> 4 waves/SIMD). Partials
// (m, l, acc) merged in-LDS at the end. K row-major bf16 swizzled, V
// transposed swizzled, swapped QK^T, P relayout via per-wave LDS, fp32 acc.
__global__ __launch_bounds__(512) void attn_split(
    const float* __restrict__ qg,
    const float* __restrict__ kg,
    const float* __restrict__ vg,
    const int* __restrict__ offs, int n_off,
    float* __restrict__ out)
{
  __shared__ __align__(16) char Kb[2][16384];
  __shared__ __align__(16) char Vb[2][16384];
  __shared__ __align__(16) char Pb[8][2048];

  const int t    = threadIdx.x;
  const int lane = t & 63;
  const int w    = t >> 6;
  const int col  = lane & 15;
  const int g    = lane >> 4;
  const int half = w >> 2;   // 0: first KV half, 1: second KV half
  const int wq   = w & 3;    // q-subtile within block
  const int th   = t & 255;  // thread index within the half (staging)

  const int h  = blockIdx.x & 15;
  const int q0 = (31 - (blockIdx.x >> 4)) * 64;  // largest-work blocks first

  const float* qh = qg + (size_t)h * SL * DM;
  const float* kh = kg + (size_t)h * SL * DM;
  const float* vh = vg + (size_t)h * SL * DM;

  const float scale = 0.08838834764831843f; // 1/sqrt(128)

  const int qrow = q0 + 16 * wq + col;
  int qstart = 0;
  for (int i = 0; i < n_off; ++i) { int o = offs[i]; if (o <= qrow) qstart = o; }
  int kv_lo = 0;
  for (int i = 0; i < n_off; ++i) { int o = offs[i]; if (o <= q0) kv_lo = o; }
  const int n  = ((q0 + 64) - kv_lo) >> 6;  // total KV tiles for this block
  const int nh = (n + 1) >> 1;              // tiles per half (loop trip count)

  // Q fragment, pre-scaled. Layout: lane holds [row=lane&15][k=8*(lane>>4)+j]
  s16x8 qf[4];
  #pragma unroll
  for (int kk = 0; kk < 4; ++kk) {
    const float* qp = qh + (size_t)qrow * DM + 32 * kk + 8 * g;
    f32x4 lo = *(const f32x4*)qp;
    f32x4 hi = *(const f32x4*)(qp + 4);
    s16x8 f;
    f[0] = f2bf(lo[0] * scale); f[1] = f2bf(lo[1] * scale);
    f[2] = f2bf(lo[2] * scale); f[3] = f2bf(lo[3] * scale);
    f[4] = f2bf(hi[0] * scale); f[5] = f2bf(hi[1] * scale);
    f[6] = f2bf(hi[2] * scale); f[7] = f2bf(hi[3] * scale);
    qf[kk] = f;
  }

  f32x4 acc[8];
  #pragma unroll
  for (int dt = 0; dt < 8; ++dt) { f32x4 zv = {0.f, 0.f, 0.f, 0.f}; acc[dt] = zv; }
  float m_ = -1e30f, l_ = 0.f;

  char* pb = &Pb[w][0];
  char* kb = &Kb[half][0];
  char* vb = &Vb[half][0];

  for (int it = 0; it < nh; ++it) {
    const int T   = half ? (nh + it) : it;
    const bool act = (T < n);            // half B may have one fewer tile
    const int kv0 = kv_lo + (T << 6);

    // ---- stage K (row-major) and V (transposed), fp32 -> bf16, swizzled ----
    if (act) {
      const float* ks = kh + (size_t)kv0 * DM;
      const float* vs = vh + (size_t)kv0 * DM;
      const int d0 = (th & 31) * 4;
      const int r0 = th >> 5;
      #pragma unroll
      for (int ri = 0; ri < 8; ++ri) {
        int r = r0 + 8 * ri;
        f32x4 f = *(const f32x4*)(ks + (size_t)r * DM + d0);
        s16x4 b;
        b[0] = f2bf(f[0]); b[1] = f2bf(f[1]); b[2] = f2bf(f[2]); b[3] = f2bf(f[3]);
        *(s16x4*)(kb + ((r * 256 + d0 * 2) ^ ((r & 7) << 4))) = b;
      }
      const int rot = (th >> 1) & 3;  // spread d&7 across XOR slots per write
      #pragma unroll
      for (int ki = 0; ki < 2; ++ki) {
        int k0 = r0 * 4 + 32 * ki;
        f32x4 a0 = *(const f32x4*)(vs + (size_t)(k0 + 0) * DM + d0);
        f32x4 a1 = *(const f32x4*)(vs + (size_t)(k0 + 1) * DM + d0);
        f32x4 a2 = *(const f32x4*)(vs + (size_t)(k0 + 2) * DM + d0);
        f32x4 a3 = *(const f32x4*)(vs + (size_t)(k0 + 3) * DM + d0);
        #pragma unroll
        for (int di = 0; di < 4; ++di) {
          int dd = (di + rot) & 3;
          int d = d0 + dd;
          s16x4 b;
          b[0] = f2bf(a0[dd]); b[1] = f2bf(a1[dd]); b[2] = f2bf(a2[dd]); b[3] = f2bf(a3[dd]);
          *(s16x4*)(vb + ((d * 128 + k0 * 2) ^ ((d & 7) << 4))) = b;
        }
      }
    }
    __syncthreads();

    if (act) {
      // ---- QK^T (swapped): st[kt] = K_tile_kt . Q^T -> S^T[k][q] ----
      f32x4 st[4];
      #pragma unroll
      for (int kt = 0; kt < 4; ++kt) { f32x4 zv = {0.f, 0.f, 0.f, 0.f}; st[kt] = zv; }
      __builtin_amdgcn_s_setprio(1);
      #pragma unroll
      for (int kt = 0; kt < 4; ++kt) {
        int row = kt * 16 + col;
        #pragma unroll
        for (int kk = 0; kk < 4; ++kk) {
          s16x8 kf = *(const s16x8*)(kb + ((row * 256 + 64 * kk + 16 * g) ^ ((row & 7) << 4)));
          st[kt] = __builtin_amdgcn_mfma_f32_16x16x32_bf16(kf, qf[kk], st[kt], 0, 0, 0);
        }
      }
      __builtin_amdgcn_s_setprio(0);

      // ---- online softmax; write P (bf16) to per-wave LDS ----
      float cm = -3.0e38f;
      #pragma unroll
      for (int kt = 0; kt < 4; ++kt) {
        #pragma unroll
        for (int r = 0; r < 4; ++r) {
          int kpos = kv0 + kt * 16 + 4 * g + r;
          float x = st[kt][r];
          bool ok = (kpos <= qrow) && (kpos >= qstart);
          x = ok ? x : -3.0e38f;
          st[kt][r] = x;
          cm = fmaxf(cm, x);
        }
      }
      cm = fmaxf(cm, __shfl_xor(cm, 16));
      cm = fmaxf(cm, __shfl_xor(cm, 32));
      float mn = fmaxf(m_, cm);
      float al = __expf(m_ - mn);
      m_ = mn;
      float psum = 0.f;
      #pragma unroll
      for (int kt = 0; kt < 4; ++kt) {
        s16x4 pk;
        #pragma unroll
        for (int r = 0; r < 4; ++r) {
          float pe = __expf(st[kt][r] - mn);
          psum += pe;
          pk[r] = f2bf(pe);
        }
        *(s16x4*)(pb + ((col * 128 + 32 * kt + 8 * g) ^ ((col & 7) << 4))) = pk;
      }
      psum += __shfl_xor(psum, 16);
      psum += __shfl_xor(psum, 32);
      l_ = l_ * al + psum;

      // ---- rescale O by alpha (per output row 4g+r) ----
      #pragma unroll
      for (int r = 0; r < 4; ++r) {
        float ar = __shfl(al, 4 * g + r);
        #pragma unroll
        for (int dt = 0; dt < 8; ++dt) acc[dt][r] *= ar;
      }

      // cross-lane LDS RAW (same wave): drain P writes before fragment reads
      asm volatile("s_waitcnt lgkmcnt(0)" ::: "memory");
      __builtin_amdgcn_sched_barrier(0);

      // ---- PV: acc[dt] += P . V ----
      __builtin_amdgcn_s_setprio(1);
      #pragma unroll
      for (int ksel = 0; ksel < 2; ++ksel) {
        s16x8 pa = *(const s16x8*)(pb + ((col * 128 + 64 * ksel + 16 * g) ^ ((col & 7) << 4)));
        #pragma unroll
        for (int dt = 0; dt < 8; ++dt) {
          int d = dt * 16 + col;
          s16x8 vf = *(const s16x8*)(vb + ((d * 128 + 64 * ksel + 16 * g) ^ ((d & 7) << 4)));
          acc[dt] = __builtin_amdgcn_mfma_f32_16x16x32_bf16(pa, vf, acc[dt], 0, 0, 0);
        }
      }
      __builtin_amdgcn_s_setprio(0);
    }
    __syncthreads();
  }

  // ---- merge the two halves' partials via LDS (reuse Kb/Vb) ----
  char* mac = &Kb[0][0];   // 32KB: 4 waves x 64 lanes x 8 f32x4
  char* mml = &Vb[0][0];   // m,l pairs
  if (half) {
    #pragma unroll
    for (int dt = 0; dt < 8; ++dt)
      *(f32x4*)(mac + (wq * 64 + lane) * 128 + ((dt ^ (lane & 7)) * 16)) = acc[dt];
    *(float2*)(mml + (wq * 64 + lane) * 8) = make_float2(m_, l_);
  }
  __syncthreads();
  if (!half) {
    float2 ml = *(const float2*)(mml + (wq * 64 + lane) * 8);
    float mm   = fmaxf(m_, ml.x);
    float eA   = __expf(m_ - mm);
    float eB   = __expf(ml.x - mm);
    float linv = 1.f / (l_ * eA + ml.y * eB);
    float fa = eA * linv, fb = eB * linv;
    #pragma unroll
    for (int dt = 0; dt < 8; ++dt) {
      f32x4 aB = *(const f32x4*)(mac + (wq * 64 + lane) * 128 + ((dt ^ (lane & 7)) * 16));
      #pragma unroll
      for (int r = 0; r < 4; ++r) {
        float a = __shfl(fa, 4 * g + r);
        float b = __shfl(fb, 4 * g + r);
        int row = q0 + 16 * wq + 4 * g + r;
        out[((size_t)h * SL + row) * DM + dt * 16 + col] = acc[dt][r] * a + aB[r] * b;
      }
    }
  }
}

extern "C" void kernel_launch(void* const* d_in, const int* in_sizes, int n_in,
                              void* d_out, int out_size, void* d_ws, size_t ws_size,
                              hipStream_t stream) {
  const float* q = (const float*)d_in[0];
  const float* k = (const float*)d_in[1];
  const float* v = (const float*)d_in[2];
  const int* offs = (const int*)d_in[3];
  const int n_off = in_sizes[3];
  float* out = (float*)d_out;

  const int blocks = NH * (SL / 64); // 16 heads x 32 q-blocks = 512
  attn_split<<<blocks, 512, 0, stream>>>(q, k, v, offs, n_off, out);
}

// Round 7
// 29.281 us; speedup vs baseline: 1.5439x; 1.5439x over previous
//
#include <hip/hip_runtime.h>
#include <hip/hip_bf16.h>
#include <math.h>

#define NH 16
#define SL 2048
#define DM 128

typedef float f32x4 __attribute__((ext_vector_type(4)));
typedef short s16x8 __attribute__((ext_vector_type(8)));
typedef short s16x4 __attribute__((ext_vector_type(4)));

static __device__ __forceinline__ short f2bf(float f) {
  __hip_bfloat16 h = __float2bfloat16(f);
  return __builtin_bit_cast(short, h);
}

// 4-wave block = 64 q-rows (wave w: rows q0+16w..+15). KV tile 64, K row-major
// bf16 swizzled, V transposed swizzled. Swapped QK^T (mfma(K,Q) -> S^T).
// Register-staged double-buffered K/V: global loads for tile t+1 issued before
// tile t's compute, convert+ds_write after, ONE barrier per tile. fp32 acc.
// Complementary block pairing: co-resident blocks sum to 9 tiles.
__global__ __launch_bounds__(256) void attn_dbuf(
    const float* __restrict__ qg,
    const float* __restrict__ kg,
    const float* __restrict__ vg,
    const int* __restrict__ offs, int n_off,
    float* __restrict__ out)
{
  __shared__ __align__(16) char Kb[2][16384];
  __shared__ __align__(16) char Vb[2][16384];
  __shared__ __align__(16) char Pb[4][2048];

  const int t    = threadIdx.x;
  const int lane = t & 63;
  const int w    = t >> 6;
  const int col  = lane & 15;
  const int g    = lane >> 4;

  // complementary pairing: blocks b (z=0: 8-u tiles) and b+256 (z=1: u+1) pair to 9
  const int blk = blockIdx.x;
  const int z   = blk >> 8;
  const int y   = (blk >> 4) & 15;
  const int h   = blk & 15;
  const int dno = y >> 2, u = y & 3;
  const int p   = z ? u : 7 - u;
  const int q0  = (dno * 8 + p) * 64;

  const float* qh = qg + (size_t)h * SL * DM;
  const float* kh = kg + (size_t)h * SL * DM;
  const float* vh = vg + (size_t)h * SL * DM;

  const float scale = 0.08838834764831843f; // 1/sqrt(128)

  const int qrow = q0 + 16 * w + col;
  int qstart = 0;
  for (int i = 0; i < n_off; ++i) { int o = offs[i]; if (o <= qrow) qstart = o; }
  int kv_lo = 0;
  for (int i = 0; i < n_off; ++i) { int o = offs[i]; if (o <= q0) kv_lo = o; }
  const int n = ((q0 + 64) - kv_lo) >> 6;  // KV tiles for this block

  // Q fragment, pre-scaled. Layout: lane holds [row=lane&15][k=8*(lane>>4)+j]
  s16x8 qf[4];
  #pragma unroll
  for (int kk = 0; kk < 4; ++kk) {
    const float* qp = qh + (size_t)qrow * DM + 32 * kk + 8 * g;
    f32x4 lo = *(const f32x4*)qp;
    f32x4 hi = *(const f32x4*)(qp + 4);
    s16x8 f;
    f[0] = f2bf(lo[0] * scale); f[1] = f2bf(lo[1] * scale);
    f[2] = f2bf(lo[2] * scale); f[3] = f2bf(lo[3] * scale);
    f[4] = f2bf(hi[0] * scale); f[5] = f2bf(hi[1] * scale);
    f[6] = f2bf(hi[2] * scale); f[7] = f2bf(hi[3] * scale);
    qf[kk] = f;
  }

  f32x4 acc[8];
  #pragma unroll
  for (int dt = 0; dt < 8; ++dt) { f32x4 zv = {0.f, 0.f, 0.f, 0.f}; acc[dt] = zv; }
  float m_ = -1e30f, l_ = 0.f;

  char* pb = &Pb[w][0];

  // staging: thread covers K rows r0+8i (cols d0..d0+3) and V rows r0*4+32k+j
  const int d0  = (t & 31) * 4;
  const int r0  = t >> 5;
  const int rot = (t >> 1) & 3;
  f32x4 kr[8], vr[8];

#define LOADT(T) do {                                                         \
    const float* _ks = kh + (size_t)(kv_lo + ((T) << 6)) * DM;                \
    const float* _vs = vh + (size_t)(kv_lo + ((T) << 6)) * DM;                \
    _Pragma("unroll")                                                         \
    for (int _i = 0; _i < 8; ++_i)                                            \
      kr[_i] = *(const f32x4*)(_ks + (size_t)(r0 + 8 * _i) * DM + d0);        \
    _Pragma("unroll")                                                         \
    for (int _k = 0; _k < 2; ++_k) {                                          \
      _Pragma("unroll")                                                       \
      for (int _j = 0; _j < 4; ++_j)                                          \
        vr[_k * 4 + _j] =                                                     \
          *(const f32x4*)(_vs + (size_t)(r0 * 4 + 32 * _k + _j) * DM + d0);   \
    }                                                                         \
  } while (0)

#define WRITEKV(B) do {                                                       \
    _Pragma("unroll")                                                         \
    for (int _i = 0; _i < 8; ++_i) {                                          \
      int _r = r0 + 8 * _i;                                                   \
      s16x4 _b;                                                               \
      _b[0] = f2bf(kr[_i][0]); _b[1] = f2bf(kr[_i][1]);                       \
      _b[2] = f2bf(kr[_i][2]); _b[3] = f2bf(kr[_i][3]);                       \
      *(s16x4*)(&Kb[B][0] + ((_r * 256 + d0 * 2) ^ ((_r & 7) << 4))) = _b;    \
    }                                                                         \
    _Pragma("unroll")                                                         \
    for (int _k = 0; _k < 2; ++_k) {                                          \
      int _k0 = r0 * 4 + 32 * _k;                                             \
      _Pragma("unroll")                                                       \
      for (int _di = 0; _di < 4; ++_di) {                                     \
        int _dd = (_di + rot) & 3;                                            \
        int _d  = d0 + _dd;                                                   \
        s16x4 _b;                                                             \
        _b[0] = f2bf(vr[_k * 4 + 0][_dd]); _b[1] = f2bf(vr[_k * 4 + 1][_dd]); \
        _b[2] = f2bf(vr[_k * 4 + 2][_dd]); _b[3] = f2bf(vr[_k * 4 + 3][_dd]); \
        *(s16x4*)(&Vb[B][0] + ((_d * 128 + _k0 * 2) ^ ((_d & 7) << 4))) = _b; \
      }                                                                       \
    }                                                                         \
  } while (0)

  // prologue: stage tile 0 into buffer 0
  LOADT(0);
  WRITEKV(0);
  int cur = 0;

  for (int it = 0; it < n; ++it) {
    const int kv0 = kv_lo + (it << 6);
    __syncthreads();                       // release writes, acquire buf[cur]

    const bool pre = (it + 1 < n);
    if (pre) LOADT(it + 1);                // issue next-tile global loads early
    __builtin_amdgcn_sched_barrier(0);     // pin loads before compute

    // ---- QK^T (swapped): st[kt] = K_tile_kt . Q^T -> S^T[k][q] ----
    f32x4 st[4];
    #pragma unroll
    for (int kt = 0; kt < 4; ++kt) { f32x4 zv = {0.f, 0.f, 0.f, 0.f}; st[kt] = zv; }
    __builtin_amdgcn_s_setprio(1);
    #pragma unroll
    for (int kt = 0; kt < 4; ++kt) {
      int row = kt * 16 + col;
      #pragma unroll
      for (int kk = 0; kk < 4; ++kk) {
        s16x8 kf = *(const s16x8*)(&Kb[cur][0] + ((row * 256 + 64 * kk + 16 * g) ^ ((row & 7) << 4)));
        st[kt] = __builtin_amdgcn_mfma_f32_16x16x32_bf16(kf, qf[kk], st[kt], 0, 0, 0);
      }
    }
    __builtin_amdgcn_s_setprio(0);

    // ---- online softmax; write P (bf16) to per-wave LDS ----
    float cm = -3.0e38f;
    #pragma unroll
    for (int kt = 0; kt < 4; ++kt) {
      #pragma unroll
      for (int r = 0; r < 4; ++r) {
        int kpos = kv0 + kt * 16 + 4 * g + r;
        float x = st[kt][r];
        bool ok = (kpos <= qrow) && (kpos >= qstart);
        x = ok ? x : -3.0e38f;
        st[kt][r] = x;
        cm = fmaxf(cm, x);
      }
    }
    cm = fmaxf(cm, __shfl_xor(cm, 16));
    cm = fmaxf(cm, __shfl_xor(cm, 32));
    float mn = fmaxf(m_, cm);
    float al = __expf(m_ - mn);
    m_ = mn;
    float psum = 0.f;
    #pragma unroll
    for (int kt = 0; kt < 4; ++kt) {
      s16x4 pk;
      #pragma unroll
      for (int r = 0; r < 4; ++r) {
        float pe = __expf(st[kt][r] - mn);
        psum += pe;
        pk[r] = f2bf(pe);
      }
      *(s16x4*)(pb + ((col * 128 + 32 * kt + 8 * g) ^ ((col & 7) << 4))) = pk;
    }
    psum += __shfl_xor(psum, 16);
    psum += __shfl_xor(psum, 32);
    l_ = l_ * al + psum;

    // ---- rescale O by alpha (per output row 4g+r) ----
    #pragma unroll
    for (int r = 0; r < 4; ++r) {
      float ar = __shfl(al, 4 * g + r);
      #pragma unroll
      for (int dt = 0; dt < 8; ++dt) acc[dt][r] *= ar;
    }

    // cross-lane LDS RAW (same wave): drain P writes before fragment reads
    asm volatile("s_waitcnt lgkmcnt(0)" ::: "memory");
    __builtin_amdgcn_sched_barrier(0);

    // ---- PV: acc[dt] += P . V ----
    __builtin_amdgcn_s_setprio(1);
    #pragma unroll
    for (int ksel = 0; ksel < 2; ++ksel) {
      s16x8 pa = *(const s16x8*)(pb + ((col * 128 + 64 * ksel + 16 * g) ^ ((col & 7) << 4)));
      #pragma unroll
      for (int dt = 0; dt < 8; ++dt) {
        int d = dt * 16 + col;
        s16x8 vf = *(const s16x8*)(&Vb[cur][0] + ((d * 128 + 64 * ksel + 16 * g) ^ ((d & 7) << 4)));
        acc[dt] = __builtin_amdgcn_mfma_f32_16x16x32_bf16(pa, vf, acc[dt], 0, 0, 0);
      }
    }
    __builtin_amdgcn_s_setprio(0);

    // ---- convert + write next tile into the other buffer ----
    if (pre) WRITEKV(cur ^ 1);
    cur ^= 1;
  }
#undef LOADT
#undef WRITEKV

  // ---- epilogue: divide by l, store fp32 ----
  #pragma unroll
  for (int r = 0; r < 4; ++r) {
    float lr  = __shfl(l_, 4 * g + r);
    float inv = 1.f / lr;
    int row   = q0 + 16 * w + 4 * g + r;
    float* op = out + ((size_t)h * SL + row) * DM + col;
    #pragma unroll
    for (int dt = 0; dt < 8; ++dt) op[dt * 16] = acc[dt][r] * inv;
  }
}

extern "C" void kernel_launch(void* const* d_in, const int* in_sizes, int n_in,
                              void* d_out, int out_size, void* d_ws, size_t ws_size,
                              hipStream_t stream) {
  const float* q = (const float*)d_in[0];
  const float* k = (const float*)d_in[1];
  const float* v = (const float*)d_in[2];
  const int* offs = (const int*)d_in[3];
  const int n_off = in_sizes[3];
  float* out = (float*)d_out;

  const int blocks = NH * (SL / 64); // 512
  attn_dbuf<<<blocks, 256, 0, stream>>>(q, k, v, offs, n_off, out);
}